// Round 1
// baseline (125.961 us; speedup 1.0000x reference)
//
#include <hip/hip_runtime.h>
#include <math.h>

// RoI max pooling, matches the JAX reference:
//   features [1, C, H, W] fp32, rois [R,4] int32 (x1,y1,x2,y2 inclusive), P=7
//   out[r,c,ph,pw] = max over h in [rb[ph],rb[ph+1}), w in [cb[pw],cb[pw+1})
//   boundaries: b[i] = trunc(x1 + fl32(rw/7) * i), all float32, NO fma
// Setup guarantees 8 <= rw, rh <= 64 (so a 64-lane wave covers the ROI width)
// and ROIs lie fully inside the feature map.

#define POOL_P 7

__global__ __launch_bounds__(256) void roipool_kernel(
    const float* __restrict__ feat, const int* __restrict__ rois,
    float* __restrict__ out, int C, int H, int W, int CG) {
  const int bid = blockIdx.x;
  const int r  = bid / CG;          // roi index
  const int cg = bid - r * CG;      // channel group (4 channels / block)
  const int wid  = threadIdx.x >> 6;   // wave id 0..3
  const int lane = threadIdx.x & 63;
  const int c = (cg << 2) + wid;       // this wave's channel

  const int4 roi = *reinterpret_cast<const int4*>(rois + 4 * r);
  const int x1 = roi.x, y1 = roi.y;
  const int rw = max(roi.z - x1 + 1, 1);
  const int rh = max(roi.w - y1 + 1, 1);

  // bin boundaries, bit-exact float32 (division, mul, add each rounded; no FMA)
  const float sx = __fdiv_rn((float)rw, (float)POOL_P);
  const float sy = __fdiv_rn((float)rh, (float)POOL_P);
  int cb[POOL_P + 1], rb[POOL_P + 1];
#pragma unroll
  for (int i = 0; i <= POOL_P; ++i) {
    cb[i] = (int)(__fadd_rn((float)x1, __fmul_rn(sx, (float)i)));  // trunc==floor (>=0)
    rb[i] = (int)(__fadd_rn((float)y1, __fmul_rn(sy, (float)i)));
  }

  const float* fc = feat + (size_t)c * H * W;
  __shared__ float lds[4][POOL_P][64];

  const bool valid = lane < rw;          // rw <= 64 per setup
  const int col = x1 + lane;
  const float NEG = -__builtin_inff();

#pragma unroll
  for (int ph = 0; ph < POOL_P; ++ph) {
    float m = NEG;
    for (int h = rb[ph]; h < rb[ph + 1]; ++h) {
      float v = valid ? fc[h * W + col] : NEG;   // coalesced 64-float row load
      m = fmaxf(m, v);
    }
    lds[wid][ph][lane] = m;
  }
  __syncthreads();

  // 49 outputs per channel: lane = ph*7+pw reduces its column-bin segment
  if (lane < POOL_P * POOL_P) {
    const int ph = lane / POOL_P;
    const int pw = lane - ph * POOL_P;
    const int w0 = cb[pw] - x1, w1 = cb[pw + 1] - x1;
    float m = NEG;
    for (int w = w0; w < w1; ++w) m = fmaxf(m, lds[wid][ph][w]);
    out[((size_t)r * C + c) * (POOL_P * POOL_P) + lane] = m;
  }
}

extern "C" void kernel_launch(void* const* d_in, const int* in_sizes, int n_in,
                              void* d_out, int out_size, void* d_ws, size_t ws_size,
                              hipStream_t stream) {
  const float* feat = (const float*)d_in[0];
  const int*   rois = (const int*)d_in[1];
  float*       out  = (float*)d_out;

  const int C = 256, H = 336, W = 336;       // fixed by setup_inputs()
  const int R = in_sizes[1] / 4;             // 256 rois
  const int CG = C / 4;                      // 4 channels per 256-thread block

  dim3 grid(R * CG), block(256);
  roipool_kernel<<<grid, block, 0, stream>>>(feat, rois, out, C, H, W, CG);
}

// Round 2
// 70.550 us; speedup vs baseline: 1.7854x; 1.7854x over previous
//
#include <hip/hip_runtime.h>
#include <math.h>

// RoI max pooling (JAX reference): features [1,C,H,W] fp32, rois [R,4] int32
// (x1,y1,x2,y2 inclusive), P=7. Boundaries b[i]=trunc(x1 + fl32(rw/7)*i),
// each op rounded separately (no FMA). Setup guarantees 8 <= rw,rh <= 64.
//
// R2: latency-bound fix — 4 channels/wave + 2x row unroll = 8 loads in
// flight per iteration (was ~1). Clamp-trick removes per-load cndmask:
// lanes >= rw load a duplicate of the last column; final reduce only reads
// w < rw so duplicates are never consumed.

#define POOL_P 7
#define NCH 4  // channels per wave

__global__ __launch_bounds__(256) void roipool_kernel(
    const float* __restrict__ feat, const int* __restrict__ rois,
    float* __restrict__ out, int C, int H, int W, int CG) {
  const int bid = blockIdx.x;
  const int r  = bid / CG;           // roi index
  const int cg = bid - r * CG;       // group of 16 channels
  const int wid  = threadIdx.x >> 6; // wave 0..3
  const int lane = threadIdx.x & 63;
  const int c0 = (cg * 4 + wid) * NCH;  // first of this wave's 4 channels

  const int4 roi = *reinterpret_cast<const int4*>(rois + 4 * r);
  const int x1 = roi.x, y1 = roi.y;
  const int rw = max(roi.z - x1 + 1, 1);
  const int rh = max(roi.w - y1 + 1, 1);

  // bit-exact fp32 boundaries: div, mul, add each rounded; trunc==floor (>=0)
  const float sx = __fdiv_rn((float)rw, (float)POOL_P);
  const float sy = __fdiv_rn((float)rh, (float)POOL_P);
  int cb[POOL_P + 1], rb[POOL_P + 1];
#pragma unroll
  for (int i = 0; i <= POOL_P; ++i) {
    cb[i] = (int)(__fadd_rn((float)x1, __fmul_rn(sx, (float)i)));
    rb[i] = (int)(__fadd_rn((float)y1, __fmul_rn(sy, (float)i)));
  }

  const size_t HW = (size_t)H * W;
  const int col = x1 + min(lane, rw - 1);  // clamp: always in-bounds
  const float* pb = feat + (size_t)c0 * HW + col;
  const float NEG = -__builtin_inff();

  __shared__ float lds[4][NCH][POOL_P][64];

#pragma unroll
  for (int ph = 0; ph < POOL_P; ++ph) {
    float m0 = NEG, m1 = NEG, m2 = NEG, m3 = NEG;
    int h = rb[ph];
    const int hend = rb[ph + 1];
    for (; h + 1 < hend; h += 2) {          // 8 independent loads in flight
      const float* p0 = pb + (size_t)h * W;
      const float* p1 = p0 + W;
      float a0 = p0[0],      b0 = p1[0];
      float a1 = p0[HW],     b1 = p1[HW];
      float a2 = p0[2 * HW], b2 = p1[2 * HW];
      float a3 = p0[3 * HW], b3 = p1[3 * HW];
      m0 = fmaxf(m0, fmaxf(a0, b0));
      m1 = fmaxf(m1, fmaxf(a1, b1));
      m2 = fmaxf(m2, fmaxf(a2, b2));
      m3 = fmaxf(m3, fmaxf(a3, b3));
    }
    if (h < hend) {                          // odd tail row
      const float* p0 = pb + (size_t)h * W;
      m0 = fmaxf(m0, p0[0]);
      m1 = fmaxf(m1, p0[HW]);
      m2 = fmaxf(m2, p0[2 * HW]);
      m3 = fmaxf(m3, p0[3 * HW]);
    }
    lds[wid][0][ph][lane] = m0;
    lds[wid][1][ph][lane] = m1;
    lds[wid][2][ph][lane] = m2;
    lds[wid][3][ph][lane] = m3;
  }
  __syncthreads();

  // 49 outputs per channel: lane = ph*7+pw reduces its column-bin segment
  if (lane < POOL_P * POOL_P) {
    const int ph = lane / POOL_P;
    const int pw = lane - ph * POOL_P;
    const int w0 = cb[pw] - x1, w1 = cb[pw + 1] - x1;
#pragma unroll
    for (int k = 0; k < NCH; ++k) {
      float m = NEG;
      for (int w = w0; w < w1; ++w) m = fmaxf(m, lds[wid][k][ph][w]);
      out[((size_t)r * C + c0 + k) * (POOL_P * POOL_P) + lane] = m;
    }
  }
}

extern "C" void kernel_launch(void* const* d_in, const int* in_sizes, int n_in,
                              void* d_out, int out_size, void* d_ws, size_t ws_size,
                              hipStream_t stream) {
  const float* feat = (const float*)d_in[0];
  const int*   rois = (const int*)d_in[1];
  float*       out  = (float*)d_out;

  const int C = 256, H = 336, W = 336;   // fixed by setup_inputs()
  const int R = in_sizes[1] / 4;         // 256 rois
  const int CG = C / (4 * NCH);          // 16 channels per 256-thread block

  dim3 grid(R * CG), block(256);
  roipool_kernel<<<grid, block, 0, stream>>>(feat, rois, out, C, H, W, CG);
}